// Round 1
// baseline (397.309 us; speedup 1.0000x reference)
//
#include <hip/hip_runtime.h>
#include <hip/hip_bf16.h>

typedef __bf16 bf16x8 __attribute__((ext_vector_type(8)));
typedef float f32x4 __attribute__((ext_vector_type(4)));

#define MFMA16 __builtin_amdgcn_mfma_f32_16x16x32_bf16

static constexpr int Bsz = 4, T = 4096, C = 1024, H = 128;
static constexpr int BT = Bsz * T; // 16384

// ---------------- kernel 0: W fp32[1024][128] -> WT bf16[128][1024] --------
__global__ __launch_bounds__(256) void k_transpose_w(
    const float* __restrict__ Wq, const float* __restrict__ Wk,
    const float* __restrict__ Wv,
    __bf16* __restrict__ WTq, __bf16* __restrict__ WTk, __bf16* __restrict__ WTv)
{
    const float* W = blockIdx.y == 0 ? Wq : (blockIdx.y == 1 ? Wk : Wv);
    __bf16* WT     = blockIdx.y == 0 ? WTq : (blockIdx.y == 1 ? WTk : WTv);
    int idx = blockIdx.x * 256 + threadIdx.x;   // 0..131071
    int n = idx >> 10, k = idx & 1023;
    WT[idx] = (__bf16)W[k * H + n];
}

// ---------------- kernel 1: projections ------------------------------------
// mode 0: Qp = ix@Wq  [BT][H] bf16 (row-major)
// mode 1: Kp = ix@Wk  [BT][H] bf16 (row-major)
// mode 2: VT = (ix@Wv)^T as [B][H][T] bf16
__global__ __launch_bounds__(256) void k_proj(
    const float* __restrict__ X,
    const __bf16* __restrict__ WTq, const __bf16* __restrict__ WTk,
    const __bf16* __restrict__ WTv,
    __bf16* __restrict__ Qp, __bf16* __restrict__ Kp, __bf16* __restrict__ VT)
{
    int mode = blockIdx.y;
    const __bf16* WT = mode == 0 ? WTq : (mode == 1 ? WTk : WTv);
    int lane = threadIdx.x & 63, w = threadIdx.x >> 6;
    int c = lane & 15, hi = lane >> 4;

    if (mode < 2) {
        __bf16* O = (mode == 0) ? Qp : Kp;
        int row = blockIdx.x * 64 + w * 16;
        const float* xp = X + (size_t)(row + c) * C + hi * 8;
        f32x4 acc[8];
        #pragma unroll
        for (int i = 0; i < 8; ++i) acc[i] = (f32x4){0.f, 0.f, 0.f, 0.f};
        for (int kk = 0; kk < C; kk += 32) {
            float4 f0 = *(const float4*)(xp + kk);
            float4 f1 = *(const float4*)(xp + kk + 4);
            bf16x8 a;
            a[0] = (__bf16)f0.x; a[1] = (__bf16)f0.y; a[2] = (__bf16)f0.z; a[3] = (__bf16)f0.w;
            a[4] = (__bf16)f1.x; a[5] = (__bf16)f1.y; a[6] = (__bf16)f1.z; a[7] = (__bf16)f1.w;
            #pragma unroll
            for (int nt = 0; nt < 8; ++nt) {
                bf16x8 b = *(const bf16x8*)(WT + (size_t)(nt * 16 + c) * C + kk + hi * 8);
                acc[nt] = MFMA16(a, b, acc[nt], 0, 0, 0);
            }
        }
        #pragma unroll
        for (int nt = 0; nt < 8; ++nt)
            #pragma unroll
            for (int r = 0; r < 4; ++r)
                O[(size_t)(row + hi * 4 + r) * H + nt * 16 + c] = (__bf16)acc[nt][r];
    } else {
        // VT[b][d][t] = sum_k Wv[k][d] * X[t][k]   (A = Wv^T, B = X^T)
        int t0 = blockIdx.x * 64;
        int d0 = w * 32;
        f32x4 acc[2][4];
        #pragma unroll
        for (int i = 0; i < 2; ++i)
            #pragma unroll
            for (int j = 0; j < 4; ++j) acc[i][j] = (f32x4){0.f, 0.f, 0.f, 0.f};
        for (int kk = 0; kk < C; kk += 32) {
            bf16x8 a0 = *(const bf16x8*)(WT + (size_t)(d0 + c) * C + kk + hi * 8);
            bf16x8 a1 = *(const bf16x8*)(WT + (size_t)(d0 + 16 + c) * C + kk + hi * 8);
            #pragma unroll
            for (int ni = 0; ni < 4; ++ni) {
                const float* xq = X + (size_t)(t0 + ni * 16 + c) * C + kk + hi * 8;
                float4 f0 = *(const float4*)xq;
                float4 f1 = *(const float4*)(xq + 4);
                bf16x8 bb;
                bb[0] = (__bf16)f0.x; bb[1] = (__bf16)f0.y; bb[2] = (__bf16)f0.z; bb[3] = (__bf16)f0.w;
                bb[4] = (__bf16)f1.x; bb[5] = (__bf16)f1.y; bb[6] = (__bf16)f1.z; bb[7] = (__bf16)f1.w;
                acc[0][ni] = MFMA16(a0, bb, acc[0][ni], 0, 0, 0);
                acc[1][ni] = MFMA16(a1, bb, acc[1][ni], 0, 0, 0);
            }
        }
        int bb_ = t0 >> 12;          // batch
        int tt0 = t0 & (T - 1);      // t within batch
        #pragma unroll
        for (int mi = 0; mi < 2; ++mi)
            #pragma unroll
            for (int ni = 0; ni < 4; ++ni)
                #pragma unroll
                for (int r = 0; r < 4; ++r)
                    VT[((size_t)bb_ * H + d0 + mi * 16 + hi * 4 + r) * T + tt0 + ni * 16 + c] =
                        (__bf16)acc[mi][ni][r];
    }
}

// ---------------- kernel 2: causal flash attention -------------------------
// wei[t,s] = Ka[t,:]·Qb[s,:] * 1/32 ; out[t,:] = softmax_s(wei) @ V
__global__ __launch_bounds__(256) void k_attn(
    const __bf16* __restrict__ Ka,   // row/"query" matrix = k_proj [BT][H]
    const __bf16* __restrict__ Qb,   // col/"key"  matrix  = q_proj [BT][H]
    const __bf16* __restrict__ VT,   // [B][H][T]
    float* __restrict__ Out)         // [BT][H] fp32
{
    __shared__ __bf16 vt[128][40];      // V tile, [d][s_local] (padded)
    __shared__ __bf16 pl[4][16][40];    // per-wave P tile (padded)

    int lane = threadIdx.x & 63, w = threadIdx.x >> 6;
    int c = lane & 15, hi = lane >> 4;
    int b = blockIdx.y, qt = blockIdx.x;
    int t0 = qt * 64 + w * 16;

    // A fragments: 16 rows of Ka for this wave, all of H=128 (4 K-chunks)
    bf16x8 qf[4];
    const __bf16* Arow = Ka + ((size_t)b * T + t0 + c) * H + hi * 8;
    #pragma unroll
    for (int kc = 0; kc < 4; ++kc) qf[kc] = *(const bf16x8*)(Arow + kc * 32);

    f32x4 o[8];
    #pragma unroll
    for (int i = 0; i < 8; ++i) o[i] = (f32x4){0.f, 0.f, 0.f, 0.f};
    float m[4], l[4];
    int trow[4];
    #pragma unroll
    for (int r = 0; r < 4; ++r) { m[r] = -1e30f; l[r] = 0.f; trow[r] = t0 + hi * 4 + r; }

    const __bf16* Bb = Qb + (size_t)b * T * H;
    const __bf16* Vb = VT + (size_t)b * H * T;
    int nst = 2 * qt + 2;

    for (int st = 0; st < nst; ++st) {
        int s0 = st * 32;
        __syncthreads();
        {   // stage V tile [128 d][32 s] -> LDS (coalesced 32B/thread)
            int d = threadIdx.x >> 1, half = threadIdx.x & 1;
            const __bf16* src = Vb + (size_t)d * T + s0 + half * 16;
            uint4 u0 = *(const uint4*)src;
            uint4 u1 = *(const uint4*)(src + 8);
            *(uint4*)&vt[d][half * 16]     = u0;
            *(uint4*)&vt[d][half * 16 + 8] = u1;
        }
        // S = Ka(t) · Qb(s)^T : two 16-col tiles
        f32x4 sa0 = (f32x4){0.f, 0.f, 0.f, 0.f};
        f32x4 sa1 = (f32x4){0.f, 0.f, 0.f, 0.f};
        #pragma unroll
        for (int kc = 0; kc < 4; ++kc) {
            bf16x8 b0 = *(const bf16x8*)(Bb + (size_t)(s0 + c) * H + kc * 32 + hi * 8);
            bf16x8 b1 = *(const bf16x8*)(Bb + (size_t)(s0 + 16 + c) * H + kc * 32 + hi * 8);
            sa0 = MFMA16(qf[kc], b0, sa0, 0, 0, 0);
            sa1 = MFMA16(qf[kc], b1, sa1, 0, 0, 0);
        }
        // online softmax (wave-parallel, 16-lane groups own 4 rows each)
        #pragma unroll
        for (int r = 0; r < 4; ++r) {
            float v0 = sa0[r] * 0.03125f;
            float v1 = sa1[r] * 0.03125f;
            if (s0 + c > trow[r])      v0 = -1e30f;
            if (s0 + 16 + c > trow[r]) v1 = -1e30f;
            float rm = fmaxf(v0, v1);
            #pragma unroll
            for (int off = 1; off < 16; off <<= 1) rm = fmaxf(rm, __shfl_xor(rm, off));
            float mn = fmaxf(m[r], rm);
            float alpha = __expf(m[r] - mn);
            v0 = __expf(v0 - mn);
            v1 = __expf(v1 - mn);
            float rs = v0 + v1;
            #pragma unroll
            for (int off = 1; off < 16; off <<= 1) rs += __shfl_xor(rs, off);
            l[r] = l[r] * alpha + rs;
            m[r] = mn;
            #pragma unroll
            for (int nt = 0; nt < 8; ++nt) o[nt][r] *= alpha;
            pl[w][hi * 4 + r][c]      = (__bf16)v0;
            pl[w][hi * 4 + r][16 + c] = (__bf16)v1;
        }
        // P fragment (A-operand layout) from wave-private LDS
        bf16x8 pf = *(const bf16x8*)&pl[w][c][hi * 8];
        __syncthreads();   // vt ready for everyone
        #pragma unroll
        for (int nt = 0; nt < 8; ++nt) {
            bf16x8 vb = *(const bf16x8*)&vt[nt * 16 + c][hi * 8];
            o[nt] = MFMA16(pf, vb, o[nt], 0, 0, 0);
        }
    }

    #pragma unroll
    for (int r = 0; r < 4; ++r) l[r] = 1.0f / l[r];
    float* orow = Out + ((size_t)b * T + t0) * H;
    #pragma unroll
    for (int nt = 0; nt < 8; ++nt)
        #pragma unroll
        for (int r = 0; r < 4; ++r)
            orow[(size_t)(hi * 4 + r) * H + nt * 16 + c] = o[nt][r] * l[r];
}

extern "C" void kernel_launch(void* const* d_in, const int* in_sizes, int n_in,
                              void* d_out, int out_size, void* d_ws, size_t ws_size,
                              hipStream_t stream) {
    const float* ix = (const float*)d_in[0];
    const float* Wq = (const float*)d_in[1];
    const float* Wk = (const float*)d_in[2];
    const float* Wv = (const float*)d_in[3];
    float* out = (float*)d_out;

    // workspace layout (bf16 elements)
    __bf16* WTq = (__bf16*)d_ws;                 // 128*1024
    __bf16* WTk = WTq + 131072;
    __bf16* WTv = WTk + 131072;
    __bf16* Qp  = WTv + 131072;                  // [BT][H]
    __bf16* Kp  = Qp + (size_t)BT * H;           // [BT][H]
    __bf16* VT  = Kp + (size_t)BT * H;           // [B][H][T]
    // total: 3*131072 + 3*2097152 bf16 = ~12.75 MB

    k_transpose_w<<<dim3(512, 3), 256, 0, stream>>>(Wq, Wk, Wv, WTq, WTk, WTv);
    k_proj<<<dim3(256, 3), 256, 0, stream>>>(ix, WTq, WTk, WTv, Qp, Kp, VT);
    k_attn<<<dim3(64, 4), 256, 0, stream>>>(Kp, Qp, VT, out);
}

// Round 2
// 224.539 us; speedup vs baseline: 1.7694x; 1.7694x over previous
//
#include <hip/hip_runtime.h>
#include <hip/hip_bf16.h>

typedef __bf16 bf16x8 __attribute__((ext_vector_type(8)));
typedef float f32x4 __attribute__((ext_vector_type(4)));

#define MFMA16 __builtin_amdgcn_mfma_f32_16x16x32_bf16

static constexpr int Bsz = 4, T = 4096, C = 1024, H = 128;
static constexpr int BT = Bsz * T; // 16384

// ---------------- kernel 0: W fp32[1024][128] -> WT bf16[128][1024] --------
__global__ __launch_bounds__(256) void k_transpose_w(
    const float* __restrict__ Wq, const float* __restrict__ Wk,
    const float* __restrict__ Wv,
    __bf16* __restrict__ WTq, __bf16* __restrict__ WTk, __bf16* __restrict__ WTv)
{
    const float* W = blockIdx.y == 0 ? Wq : (blockIdx.y == 1 ? Wk : Wv);
    __bf16* WT     = blockIdx.y == 0 ? WTq : (blockIdx.y == 1 ? WTk : WTv);
    int idx = blockIdx.x * 256 + threadIdx.x;   // 0..131071
    int n = idx >> 10, k = idx & 1023;
    WT[idx] = (__bf16)W[k * H + n];
}

// ---------------- kernel 1: fused QKV projection ---------------------------
// Reads X once. Qp,Kp row-major [BT][H]; VT transposed [B][H][T].
__global__ __launch_bounds__(256) void k_proj_fused(
    const float* __restrict__ X,
    const __bf16* __restrict__ WTq, const __bf16* __restrict__ WTk,
    const __bf16* __restrict__ WTv,
    __bf16* __restrict__ Qp, __bf16* __restrict__ Kp, __bf16* __restrict__ VT)
{
    __shared__ __bf16 vt_l[128][72];   // [d][t_local] padded (144B rows, 16B-aligned)

    int lane = threadIdx.x & 63, w = threadIdx.x >> 6;
    int c = lane & 15, hi = lane >> 4;
    int g0 = blockIdx.x * 64;          // 64 global rows per block
    int row = g0 + w * 16;

    const float* xp = X + (size_t)(row + c) * C + hi * 8;
    f32x4 aq[8], ak[8], av[8];
    #pragma unroll
    for (int i = 0; i < 8; ++i) { aq[i] = (f32x4){0,0,0,0}; ak[i] = aq[i]; av[i] = aq[i]; }

    for (int kk = 0; kk < C; kk += 32) {
        float4 f0 = *(const float4*)(xp + kk);
        float4 f1 = *(const float4*)(xp + kk + 4);
        bf16x8 a;
        a[0] = (__bf16)f0.x; a[1] = (__bf16)f0.y; a[2] = (__bf16)f0.z; a[3] = (__bf16)f0.w;
        a[4] = (__bf16)f1.x; a[5] = (__bf16)f1.y; a[6] = (__bf16)f1.z; a[7] = (__bf16)f1.w;
        #pragma unroll
        for (int nt = 0; nt < 8; ++nt) {
            size_t boff = (size_t)(nt * 16 + c) * C + kk + hi * 8;
            bf16x8 bq = *(const bf16x8*)(WTq + boff);
            bf16x8 bk = *(const bf16x8*)(WTk + boff);
            bf16x8 bv = *(const bf16x8*)(WTv + boff);
            aq[nt] = MFMA16(a, bq, aq[nt], 0, 0, 0);
            ak[nt] = MFMA16(a, bk, ak[nt], 0, 0, 0);
            av[nt] = MFMA16(a, bv, av[nt], 0, 0, 0);
        }
    }

    // Q, K row-major stores
    #pragma unroll
    for (int nt = 0; nt < 8; ++nt)
        #pragma unroll
        for (int r = 0; r < 4; ++r) {
            size_t o = (size_t)(row + hi * 4 + r) * H + nt * 16 + c;
            Qp[o] = (__bf16)aq[nt][r];
            Kp[o] = (__bf16)ak[nt][r];
        }

    // V -> LDS (transposed) -> coalesced VT write
    #pragma unroll
    for (int nt = 0; nt < 8; ++nt)
        #pragma unroll
        for (int r = 0; r < 4; ++r)
            vt_l[nt * 16 + c][w * 16 + hi * 4 + r] = (__bf16)av[nt][r];
    __syncthreads();

    int d = threadIdx.x >> 1, half = threadIdx.x & 1;
    int b = g0 >> 12, tl = g0 & (T - 1);
    __bf16* dst = VT + ((size_t)b * H + d) * T + tl + half * 32;
    const __bf16* srcl = &vt_l[d][half * 32];
    uint4 u0 = *(const uint4*)(srcl + 0);
    uint4 u1 = *(const uint4*)(srcl + 8);
    uint4 u2 = *(const uint4*)(srcl + 16);
    uint4 u3 = *(const uint4*)(srcl + 24);
    *(uint4*)(dst + 0)  = u0;
    *(uint4*)(dst + 8)  = u1;
    *(uint4*)(dst + 16) = u2;
    *(uint4*)(dst + 24) = u3;
}

// ---------------- kernel 2: causal flash attention, split-s across waves ---
// wei[t,s] = Ka[t,:]·Qb[s,:] / 32 ; out[t,:] = softmax_s(wei) @ V
// Block: 4 waves, SAME 32 q-rows; wave w takes s-tiles w, w+4, w+8, ...
__global__ __launch_bounds__(256) void k_attn(
    const __bf16* __restrict__ Ka,   // row/"query" role = k_proj [BT][H]
    const __bf16* __restrict__ Qb,   // col/"key"  role  = q_proj [BT][H]
    const __bf16* __restrict__ VT,   // [B][H][T]
    float* __restrict__ Out)         // [BT][H] fp32
{
    union SMem {
        __bf16 pl[4][32][40];        // per-wave P tile during loop
        float  oacc[32][132];        // merged O in epilogue (aliases pl - safe)
    };
    __shared__ SMem su;
    __shared__ float sm_m[4][32];
    __shared__ float sm_l[4][32];
    __shared__ float sLrow[32];

    int lane = threadIdx.x & 63, w = threadIdx.x >> 6;
    int c = lane & 15, hi = lane >> 4;

    // big-work tiles dispatched first; halves pair big+small on a CU
    int bi = blockIdx.x;
    int b, qt;
    if (bi < 256) { b = bi & 3; qt = 127 - (bi >> 2); }
    else          { int j = bi - 256; b = j & 3; qt = j >> 2; }
    int t0 = qt * 32;

    // A fragments: 32 rows of Ka (2 row-tiles), full H
    bf16x8 af[2][4];
    const __bf16* Abase = Ka + ((size_t)b * T + t0 + c) * H + hi * 8;
    #pragma unroll
    for (int mi = 0; mi < 2; ++mi)
        #pragma unroll
        for (int kc = 0; kc < 4; ++kc)
            af[mi][kc] = *(const bf16x8*)(Abase + (size_t)mi * 16 * H + kc * 32);

    f32x4 o[2][8];
    float m[2][4], l[2][4];
    #pragma unroll
    for (int mi = 0; mi < 2; ++mi) {
        #pragma unroll
        for (int nt = 0; nt < 8; ++nt) o[mi][nt] = (f32x4){0,0,0,0};
        #pragma unroll
        for (int r = 0; r < 4; ++r) { m[mi][r] = -1e30f; l[mi][r] = 0.f; }
    }

    const __bf16* Bb = Qb + (size_t)b * T * H;
    const __bf16* Vb = VT + (size_t)b * H * T;

    for (int st = w; st <= qt; st += 4) {
        int s0 = st * 32;
        f32x4 sa[2][2];
        sa[0][0] = (f32x4){0,0,0,0}; sa[0][1] = sa[0][0];
        sa[1][0] = sa[0][0];         sa[1][1] = sa[0][0];
        #pragma unroll
        for (int kc = 0; kc < 4; ++kc) {
            bf16x8 b0 = *(const bf16x8*)(Bb + (size_t)(s0 + c)      * H + kc * 32 + hi * 8);
            bf16x8 b1 = *(const bf16x8*)(Bb + (size_t)(s0 + 16 + c) * H + kc * 32 + hi * 8);
            #pragma unroll
            for (int mi = 0; mi < 2; ++mi) {
                sa[mi][0] = MFMA16(af[mi][kc], b0, sa[mi][0], 0, 0, 0);
                sa[mi][1] = MFMA16(af[mi][kc], b1, sa[mi][1], 0, 0, 0);
            }
        }
        bool diag = (st == qt);
        #pragma unroll
        for (int mi = 0; mi < 2; ++mi)
            #pragma unroll
            for (int r = 0; r < 4; ++r) {
                float v0 = sa[mi][0][r] * 0.03125f;
                float v1 = sa[mi][1][r] * 0.03125f;
                if (diag) {
                    int rowg = t0 + 16 * mi + hi * 4 + r;
                    if (s0 + c > rowg)      v0 = -1e30f;
                    if (s0 + 16 + c > rowg) v1 = -1e30f;
                }
                float rm = fmaxf(v0, v1);
                #pragma unroll
                for (int off = 1; off < 16; off <<= 1) rm = fmaxf(rm, __shfl_xor(rm, off));
                if (rm > m[mi][r]) {       // exact deferred rescale
                    float al = __expf(m[mi][r] - rm);
                    #pragma unroll
                    for (int nt = 0; nt < 8; ++nt) o[mi][nt][r] *= al;
                    l[mi][r] *= al;
                    m[mi][r] = rm;
                }
                float p0 = __expf(v0 - m[mi][r]);
                float p1 = __expf(v1 - m[mi][r]);
                float rs = p0 + p1;
                #pragma unroll
                for (int off = 1; off < 16; off <<= 1) rs += __shfl_xor(rs, off);
                l[mi][r] += rs;
                su.pl[w][16 * mi + hi * 4 + r][c]      = (__bf16)p0;
                su.pl[w][16 * mi + hi * 4 + r][16 + c] = (__bf16)p1;
            }
        // PV: O[2 row-tiles][128] += P(32x32) @ V(32x128)
        bf16x8 pf0 = *(const bf16x8*)&su.pl[w][c][hi * 8];
        bf16x8 pf1 = *(const bf16x8*)&su.pl[w][16 + c][hi * 8];
        #pragma unroll
        for (int nt = 0; nt < 8; ++nt) {
            bf16x8 vb = *(const bf16x8*)(Vb + (size_t)(nt * 16 + c) * T + s0 + hi * 8);
            o[0][nt] = MFMA16(pf0, vb, o[0][nt], 0, 0, 0);
            o[1][nt] = MFMA16(pf1, vb, o[1][nt], 0, 0, 0);
        }
    }

    // -------- merge 4 waves' partial (m, l, o) --------
    #pragma unroll
    for (int mi = 0; mi < 2; ++mi)
        #pragma unroll
        for (int r = 0; r < 4; ++r)
            if (c == 0) {
                sm_m[w][16 * mi + hi * 4 + r] = m[mi][r];
                sm_l[w][16 * mi + hi * 4 + r] = l[mi][r];
            }
    __syncthreads();

    float al[2][4];
    #pragma unroll
    for (int mi = 0; mi < 2; ++mi)
        #pragma unroll
        for (int r = 0; r < 4; ++r) {
            int row = 16 * mi + hi * 4 + r;
            float M = fmaxf(fmaxf(sm_m[0][row], sm_m[1][row]),
                            fmaxf(sm_m[2][row], sm_m[3][row]));
            al[mi][r] = __expf(m[mi][r] - M);
            if (w == 0 && c == 0) {
                float L = sm_l[0][row] * __expf(sm_m[0][row] - M)
                        + sm_l[1][row] * __expf(sm_m[1][row] - M)
                        + sm_l[2][row] * __expf(sm_m[2][row] - M)
                        + sm_l[3][row] * __expf(sm_m[3][row] - M);
                sLrow[row] = L;
            }
        }

    for (int wv = 0; wv < 4; ++wv) {
        if (w == wv) {
            #pragma unroll
            for (int mi = 0; mi < 2; ++mi)
                #pragma unroll
                for (int nt = 0; nt < 8; ++nt)
                    #pragma unroll
                    for (int r = 0; r < 4; ++r) {
                        int row = 16 * mi + hi * 4 + r, col = nt * 16 + c;
                        float v = o[mi][nt][r] * al[mi][r];
                        if (wv == 0) su.oacc[row][col] = v;
                        else         su.oacc[row][col] += v;
                    }
        }
        __syncthreads();
    }

    int tid = threadIdx.x;
    int row = tid >> 3, col0 = (tid & 7) * 16;
    float inv = 1.0f / sLrow[row];
    float* dst = Out + ((size_t)b * T + t0 + row) * H + col0;
    #pragma unroll
    for (int i = 0; i < 16; i += 4) {
        float4 v;
        v.x = su.oacc[row][col0 + i]     * inv;
        v.y = su.oacc[row][col0 + i + 1] * inv;
        v.z = su.oacc[row][col0 + i + 2] * inv;
        v.w = su.oacc[row][col0 + i + 3] * inv;
        *(float4*)(dst + i) = v;
    }
}

extern "C" void kernel_launch(void* const* d_in, const int* in_sizes, int n_in,
                              void* d_out, int out_size, void* d_ws, size_t ws_size,
                              hipStream_t stream) {
    const float* ix = (const float*)d_in[0];
    const float* Wq = (const float*)d_in[1];
    const float* Wk = (const float*)d_in[2];
    const float* Wv = (const float*)d_in[3];
    float* out = (float*)d_out;

    __bf16* WTq = (__bf16*)d_ws;                 // 128*1024
    __bf16* WTk = WTq + 131072;
    __bf16* WTv = WTk + 131072;
    __bf16* Qp  = WTv + 131072;                  // [BT][H]
    __bf16* Kp  = Qp + (size_t)BT * H;           // [BT][H]
    __bf16* VT  = Kp + (size_t)BT * H;           // [B][H][T]

    k_transpose_w<<<dim3(512, 3), 256, 0, stream>>>(Wq, Wk, Wv, WTq, WTk, WTv);
    k_proj_fused<<<dim3(256), 256, 0, stream>>>(ix, WTq, WTk, WTv, Qp, Kp, VT);
    k_attn<<<dim3(512), 256, 0, stream>>>(Kp, Qp, VT, out);
}

// Round 3
// 182.239 us; speedup vs baseline: 2.1801x; 1.2321x over previous
//
#include <hip/hip_runtime.h>
#include <hip/hip_bf16.h>

typedef __bf16 bf16x8 __attribute__((ext_vector_type(8)));
typedef float f32x4 __attribute__((ext_vector_type(4)));

#define MFMA16 __builtin_amdgcn_mfma_f32_16x16x32_bf16

static constexpr int Bsz = 4, T = 4096, C = 1024, H = 128;
static constexpr int BT = Bsz * T; // 16384

// ---------------- kernel 0: W fp32[1024][128] -> WT bf16[128][1024] --------
// Wk additionally scaled by C^-0.5 * log2(e) so attention uses exp2 directly.
__global__ __launch_bounds__(256) void k_transpose_w(
    const float* __restrict__ Wq, const float* __restrict__ Wk,
    const float* __restrict__ Wv,
    __bf16* __restrict__ WTq, __bf16* __restrict__ WTk, __bf16* __restrict__ WTv)
{
    int m = blockIdx.y;
    const float* W = m == 0 ? Wq : (m == 1 ? Wk : Wv);
    __bf16* WT     = m == 0 ? WTq : (m == 1 ? WTk : WTv);
    float s = (m == 1) ? 0.045084220f : 1.0f;   // 1/32 * log2(e)
    int idx = blockIdx.x * 256 + threadIdx.x;   // 0..131071
    int n = idx >> 10, k = idx & 1023;
    WT[idx] = (__bf16)(W[k * H + n] * s);
}

// ---------------- kernel 1: fused QKV projection ---------------------------
// 512 blocks x 128 threads (2 waves, 16 rows each). Reads X once.
__global__ __launch_bounds__(128) void k_proj_fused(
    const float* __restrict__ X,
    const __bf16* __restrict__ WTq, const __bf16* __restrict__ WTk,
    const __bf16* __restrict__ WTv,
    __bf16* __restrict__ Qp, __bf16* __restrict__ Kp, __bf16* __restrict__ VT)
{
    __shared__ __bf16 vt_l[128][40];   // [d][t_local 0..31] padded

    int lane = threadIdx.x & 63, w = threadIdx.x >> 6;   // w in {0,1}
    int c = lane & 15, hi = lane >> 4;
    int g0 = blockIdx.x * 32;
    int row = g0 + w * 16;

    const float* xp = X + (size_t)(row + c) * C + hi * 8;
    f32x4 aq[8], ak[8], av[8];
    #pragma unroll
    for (int i = 0; i < 8; ++i) { aq[i] = (f32x4){0,0,0,0}; ak[i] = aq[i]; av[i] = aq[i]; }

    #pragma unroll 2
    for (int kk = 0; kk < C; kk += 32) {
        float4 f0 = *(const float4*)(xp + kk);
        float4 f1 = *(const float4*)(xp + kk + 4);
        bf16x8 a;
        a[0] = (__bf16)f0.x; a[1] = (__bf16)f0.y; a[2] = (__bf16)f0.z; a[3] = (__bf16)f0.w;
        a[4] = (__bf16)f1.x; a[5] = (__bf16)f1.y; a[6] = (__bf16)f1.z; a[7] = (__bf16)f1.w;
        #pragma unroll
        for (int nt = 0; nt < 8; ++nt) {
            size_t boff = (size_t)(nt * 16 + c) * C + kk + hi * 8;
            bf16x8 bq = *(const bf16x8*)(WTq + boff);
            bf16x8 bk = *(const bf16x8*)(WTk + boff);
            bf16x8 bv = *(const bf16x8*)(WTv + boff);
            aq[nt] = MFMA16(a, bq, aq[nt], 0, 0, 0);
            ak[nt] = MFMA16(a, bk, ak[nt], 0, 0, 0);
            av[nt] = MFMA16(a, bv, av[nt], 0, 0, 0);
        }
    }

    #pragma unroll
    for (int nt = 0; nt < 8; ++nt)
        #pragma unroll
        for (int r = 0; r < 4; ++r) {
            size_t o = (size_t)(row + hi * 4 + r) * H + nt * 16 + c;
            Qp[o] = (__bf16)aq[nt][r];
            Kp[o] = (__bf16)ak[nt][r];
        }

    // V -> LDS transpose -> coalesced-ish VT write
    #pragma unroll
    for (int nt = 0; nt < 8; ++nt)
        #pragma unroll
        for (int r = 0; r < 4; ++r)
            vt_l[nt * 16 + c][w * 16 + hi * 4 + r] = (__bf16)av[nt][r];
    __syncthreads();

    int d = threadIdx.x;               // 0..127
    int b = g0 >> 12, tl = g0 & (T - 1);
    __bf16* dst = VT + ((size_t)b * H + d) * T + tl;
    const __bf16* srcl = &vt_l[d][0];
    uint4 u0 = *(const uint4*)(srcl + 0);
    uint4 u1 = *(const uint4*)(srcl + 8);
    uint4 u2 = *(const uint4*)(srcl + 16);
    uint4 u3 = *(const uint4*)(srcl + 24);
    *(uint4*)(dst + 0)  = u0;
    *(uint4*)(dst + 8)  = u1;
    *(uint4*)(dst + 16) = u2;
    *(uint4*)(dst + 24) = u3;
}

// ---------------- kernel 2: causal attention, no-max softmax ---------------
// wei_log2 = Ka[t,:]·Qb[s,:] (scale pre-folded into Ka); p = exp2(wei_log2)
// 1024 blocks: (work item i = (b, qt), part p). 4 waves split s stride-8.
// Part 0 writes unnormalized O to Out; part 1 to Po. l sums to Pl.
__global__ __launch_bounds__(256) void k_attn(
    const __bf16* __restrict__ Ka,   // k-projection, pre-scaled [BT][H]
    const __bf16* __restrict__ Qb,   // q-projection [BT][H]
    const __bf16* __restrict__ VT,   // [B][H][T]
    float* __restrict__ Out,         // [BT][H] fp32 (unnormalized o, part 0)
    float* __restrict__ Po,          // [BT][H] fp32 (unnormalized o, part 1)
    float* __restrict__ Pl)          // [2][4][128][32] row sums
{
    union SMem {
        __bf16 pl[4][32][40];        // per-wave P tiles during loop
        float  oacc[32][132];        // merged O in epilogue
    };
    __shared__ SMem su;
    __shared__ float sml[4][32];

    int lane = threadIdx.x & 63, w = threadIdx.x >> 6;
    int c = lane & 15, hi = lane >> 4;

    int bi = blockIdx.x;             // 0..1023, big qt dispatched first
    int i = bi >> 1, p = bi & 1;
    int b = i & 3, qt = 127 - (i >> 2);
    int t0 = qt * 32;

    const __bf16* Bb = Qb + (size_t)b * T * H;
    const __bf16* Vb = VT + (size_t)b * H * T;
    const __bf16* Abase = Ka + ((size_t)b * T + t0 + c) * H + hi * 8;

    f32x4 o[2][8], ol[2];
    #pragma unroll
    for (int mi = 0; mi < 2; ++mi) {
        #pragma unroll
        for (int nt = 0; nt < 8; ++nt) o[mi][nt] = (f32x4){0,0,0,0};
        ol[mi] = (f32x4){0,0,0,0};
    }
    bf16x8 ones;
    #pragma unroll
    for (int j = 0; j < 8; ++j) ones[j] = (__bf16)1.0f;

    for (int st = 4 * p + w; st <= qt; st += 8) {
        int s0 = st * 32;
        // A fragments (L1/L2-hot, reloaded to keep VGPR low)
        bf16x8 af0[4], af1[4];
        #pragma unroll
        for (int kc = 0; kc < 4; ++kc) {
            af0[kc] = *(const bf16x8*)(Abase + kc * 32);
            af1[kc] = *(const bf16x8*)(Abase + (size_t)16 * H + kc * 32);
        }
        f32x4 sa00 = (f32x4){0,0,0,0}, sa01 = sa00, sa10 = sa00, sa11 = sa00;
        #pragma unroll
        for (int kc = 0; kc < 4; ++kc) {
            bf16x8 b0 = *(const bf16x8*)(Bb + (size_t)(s0 + c)      * H + kc * 32 + hi * 8);
            bf16x8 b1 = *(const bf16x8*)(Bb + (size_t)(s0 + 16 + c) * H + kc * 32 + hi * 8);
            sa00 = MFMA16(af0[kc], b0, sa00, 0, 0, 0);
            sa01 = MFMA16(af0[kc], b1, sa01, 0, 0, 0);
            sa10 = MFMA16(af1[kc], b0, sa10, 0, 0, 0);
            sa11 = MFMA16(af1[kc], b1, sa11, 0, 0, 0);
        }
        bool diag = (st == qt);
        #pragma unroll
        for (int r = 0; r < 4; ++r) {
            float e00 = __builtin_amdgcn_exp2f(sa00[r]);
            float e01 = __builtin_amdgcn_exp2f(sa01[r]);
            float e10 = __builtin_amdgcn_exp2f(sa10[r]);
            float e11 = __builtin_amdgcn_exp2f(sa11[r]);
            if (diag) {
                int r0 = t0 + hi * 4 + r, r1 = r0 + 16;
                if (s0 + c > r0)      e00 = 0.f;
                if (s0 + 16 + c > r0) e01 = 0.f;
                if (s0 + c > r1)      e10 = 0.f;
                if (s0 + 16 + c > r1) e11 = 0.f;
            }
            su.pl[w][hi * 4 + r][c]           = (__bf16)e00;
            su.pl[w][hi * 4 + r][16 + c]      = (__bf16)e01;
            su.pl[w][16 + hi * 4 + r][c]      = (__bf16)e10;
            su.pl[w][16 + hi * 4 + r][16 + c] = (__bf16)e11;
        }
        bf16x8 pf0 = *(const bf16x8*)&su.pl[w][c][hi * 8];
        bf16x8 pf1 = *(const bf16x8*)&su.pl[w][16 + c][hi * 8];
        ol[0] = MFMA16(pf0, ones, ol[0], 0, 0, 0);   // row sums ride matrix pipe
        ol[1] = MFMA16(pf1, ones, ol[1], 0, 0, 0);
        #pragma unroll
        for (int nt = 0; nt < 8; ++nt) {
            bf16x8 vb = *(const bf16x8*)(Vb + (size_t)(nt * 16 + c) * T + s0 + hi * 8);
            o[0][nt] = MFMA16(pf0, vb, o[0][nt], 0, 0, 0);
            o[1][nt] = MFMA16(pf1, vb, o[1][nt], 0, 0, 0);
        }
    }

    // ---- merge across the 4 waves: plain sums (no max => no rescale) ----
    if (c == 0) {
        #pragma unroll
        for (int mi = 0; mi < 2; ++mi)
            #pragma unroll
            for (int r = 0; r < 4; ++r)
                sml[w][16 * mi + hi * 4 + r] = ol[mi][r];
    }
    __syncthreads();   // also: everyone done with su.pl

    for (int wv = 0; wv < 4; ++wv) {
        if (w == wv) {
            #pragma unroll
            for (int mi = 0; mi < 2; ++mi)
                #pragma unroll
                for (int nt = 0; nt < 8; ++nt)
                    #pragma unroll
                    for (int r = 0; r < 4; ++r) {
                        int row = 16 * mi + hi * 4 + r, col = nt * 16 + c;
                        if (wv == 0) su.oacc[row][col]  = o[mi][nt][r];
                        else         su.oacc[row][col] += o[mi][nt][r];
                    }
        }
        __syncthreads();
    }

    int tid = threadIdx.x;
    int row = tid >> 3, col0 = (tid & 7) * 16;
    float* dst = (p == 0) ? (Out + ((size_t)b * T + t0 + row) * H + col0)
                          : (Po  + ((size_t)b * T + t0 + row) * H + col0);
    #pragma unroll
    for (int ii = 0; ii < 16; ii += 4) {
        float4 v;
        v.x = su.oacc[row][col0 + ii];
        v.y = su.oacc[row][col0 + ii + 1];
        v.z = su.oacc[row][col0 + ii + 2];
        v.w = su.oacc[row][col0 + ii + 3];
        *(float4*)(dst + ii) = v;
    }
    if ((tid & 7) == 0) {
        float L = sml[0][row] + sml[1][row] + sml[2][row] + sml[3][row];
        Pl[(((size_t)p * 4 + b) * 128 + qt) * 32 + row] = L;
    }
}

// ---------------- kernel 3: merge parts + normalize ------------------------
__global__ __launch_bounds__(256) void k_merge(
    float* __restrict__ Out, const float* __restrict__ Po,
    const float* __restrict__ Pl)
{
    size_t idx = ((size_t)blockIdx.x * 256 + threadIdx.x) * 8;
    size_t row = idx >> 7;
    int b = (int)(row >> 12), t = (int)(row & (T - 1));
    int qt = t >> 5, rr = t & 31;
    float l0 = Pl[(((size_t)0 * 4 + b) * 128 + qt) * 32 + rr];
    float l1 = Pl[(((size_t)1 * 4 + b) * 128 + qt) * 32 + rr];
    float inv = 1.0f / (l0 + l1);
    float4 a0 = *(const float4*)(Out + idx);
    float4 a1 = *(const float4*)(Out + idx + 4);
    float4 p0 = *(const float4*)(Po + idx);
    float4 p1 = *(const float4*)(Po + idx + 4);
    float4 r0, r1;
    r0.x = (a0.x + p0.x) * inv; r0.y = (a0.y + p0.y) * inv;
    r0.z = (a0.z + p0.z) * inv; r0.w = (a0.w + p0.w) * inv;
    r1.x = (a1.x + p1.x) * inv; r1.y = (a1.y + p1.y) * inv;
    r1.z = (a1.z + p1.z) * inv; r1.w = (a1.w + p1.w) * inv;
    *(float4*)(Out + idx)     = r0;
    *(float4*)(Out + idx + 4) = r1;
}

extern "C" void kernel_launch(void* const* d_in, const int* in_sizes, int n_in,
                              void* d_out, int out_size, void* d_ws, size_t ws_size,
                              hipStream_t stream) {
    const float* ix = (const float*)d_in[0];
    const float* Wq = (const float*)d_in[1];
    const float* Wk = (const float*)d_in[2];
    const float* Wv = (const float*)d_in[3];
    float* out = (float*)d_out;

    __bf16* WTq = (__bf16*)d_ws;                 // 128*1024 each
    __bf16* WTk = WTq + 131072;
    __bf16* WTv = WTk + 131072;
    __bf16* Qp  = WTv + 131072;                  // [BT][H]
    __bf16* Kp  = Qp + (size_t)BT * H;
    __bf16* VT  = Kp + (size_t)BT * H;           // [B][H][T]
    float*  Po  = (float*)(VT + (size_t)BT * H); // [BT][H] fp32 partial
    float*  Pl  = Po + (size_t)BT * H;           // [2][4][128][32]
    // total ws: 13.37MB + 8.39MB + 0.13MB = ~21.9MB

    k_transpose_w<<<dim3(512, 3), 256, 0, stream>>>(Wq, Wk, Wv, WTq, WTk, WTv);
    k_proj_fused<<<dim3(512), 128, 0, stream>>>(ix, WTq, WTk, WTv, Qp, Kp, VT);
    k_attn<<<dim3(1024), 256, 0, stream>>>(Kp, Qp, VT, out, Po, Pl);
    k_merge<<<dim3(1024), 256, 0, stream>>>(out, Po, Pl);
}